// Round 3
// baseline (393.458 us; speedup 1.0000x reference)
//
#include <hip/hip_runtime.h>
#include <hip/hip_bf16.h>

typedef unsigned short u16;
typedef __bf16 bf16x8 __attribute__((ext_vector_type(8)));
typedef u16 u16x8 __attribute__((ext_vector_type(8)));
typedef float f32x4 __attribute__((ext_vector_type(4)));

__device__ __forceinline__ float bf2f(u16 u) {
  union { unsigned u32; float f; } c; c.u32 = ((unsigned)u) << 16; return c.f;
}
__device__ __forceinline__ u16 f2bf(float f) {
  union { float f; unsigned u32; } c; c.f = f;
  unsigned r = c.u32 + 0x7FFFu + ((c.u32 >> 16) & 1u);
  return (u16)(r >> 16);
}

// ---------------------------------------------------------------------------
// fp32 -> bf16 cast, 4 elems/thread. n must be divisible by 4 (it is).
// ---------------------------------------------------------------------------
__global__ __launch_bounds__(256)
void cast_f32_bf16_kernel(const float* __restrict__ in, u16* __restrict__ out,
                          int n4) {
  const int i = (blockIdx.x * 256 + threadIdx.x) * 4;
  if (i < n4) {
    float4 v = *(const float4*)(in + i);
    ushort4 o;
    o.x = f2bf(v.x); o.y = f2bf(v.y); o.z = f2bf(v.z); o.w = f2bf(v.w);
    *(ushort4*)(out + i) = o;
  }
}

// ---------------------------------------------------------------------------
// GEMM: C[M,N] = A[M,K] @ B[N,K]^T (row-major, K contiguous), bf16 in,
// fp32 accum, output bf16 (OUTF32=0) or fp32 (OUTF32=1, + fp32 bias).
// 128x128 tile, BK=32, 4 waves (2x2 of 64x64), mfma_f32_16x16x32_bf16.
// Register-staged LDS with [128][40] padding (80B rows, 2-way alias = free).
// ---------------------------------------------------------------------------
template<int BIAS, int OUTF32>
__global__ __launch_bounds__(256)
void gemm_bt_kernel(const u16* __restrict__ A, const u16* __restrict__ B,
                    void* __restrict__ Cv, const float* __restrict__ bias,
                    int M, int N, int K) {
  __shared__ alignas(16) u16 As[128][40];   // 10 KB
  __shared__ alignas(16) u16 Bs[128][40];   // 10 KB
  const int tid = threadIdx.x;
  const int l = tid & 63, w = tid >> 6;
  const int lane16 = l & 15, lg = l >> 4;
  const int wr = w >> 1, wc = w & 1;
  const int bm = blockIdx.x, bn = blockIdx.y;

  const f32x4 zero = {0.f, 0.f, 0.f, 0.f};
  f32x4 acc[4][4];
#pragma unroll
  for (int i = 0; i < 4; ++i)
#pragma unroll
    for (int j = 0; j < 4; ++j) acc[i][j] = zero;

  // staging: chunk c in [0,512) covers elems [c*8,c*8+8) of logical [128][32];
  // row=c>>2, elem=(c&3)*8. Thread owns chunks {tid, tid+256}.
  const int r0 = tid >> 2, e0 = (tid & 3) * 8;
  const u16* Ap0 = A + (size_t)(bm * 128 + r0) * K + e0;
  const u16* Ap1 = A + (size_t)(bm * 128 + r0 + 64) * K + e0;
  const u16* Bp0 = B + (size_t)(bn * 128 + r0) * K + e0;
  const u16* Bp1 = B + (size_t)(bn * 128 + r0 + 64) * K + e0;

  for (int k0 = 0; k0 < K; k0 += 32) {
    u16x8 a0 = *(const u16x8*)(Ap0 + k0);
    u16x8 a1 = *(const u16x8*)(Ap1 + k0);
    u16x8 b0 = *(const u16x8*)(Bp0 + k0);
    u16x8 b1 = *(const u16x8*)(Bp1 + k0);
    __syncthreads();               // prev-iter LDS reads complete
    *(u16x8*)&As[r0][e0] = a0;
    *(u16x8*)&As[r0 + 64][e0] = a1;
    *(u16x8*)&Bs[r0][e0] = b0;
    *(u16x8*)&Bs[r0 + 64][e0] = b1;
    __syncthreads();               // stores visible to all waves

    bf16x8 af[4], bfr[4];
#pragma unroll
    for (int i = 0; i < 4; ++i)
      af[i] = *(const bf16x8*)&As[wr * 64 + i * 16 + lane16][lg * 8];
#pragma unroll
    for (int j = 0; j < 4; ++j)
      bfr[j] = *(const bf16x8*)&Bs[wc * 64 + j * 16 + lane16][lg * 8];
#pragma unroll
    for (int i = 0; i < 4; ++i)
#pragma unroll
      for (int j = 0; j < 4; ++j)
        acc[i][j] = __builtin_amdgcn_mfma_f32_16x16x32_bf16(af[i], bfr[j], acc[i][j], 0, 0, 0);
  }

  // epilogue: D layout col = lane&15, row = (lane>>4)*4 + reg
  const int row0 = bm * 128 + wr * 64, col0 = bn * 128 + wc * 64;
#pragma unroll
  for (int i = 0; i < 4; ++i) {
#pragma unroll
    for (int j = 0; j < 4; ++j) {
      const int col = col0 + j * 16 + lane16;
      const float badd = BIAS ? bias[col] : 0.f;
      const int rbase = row0 + i * 16 + lg * 4;
#pragma unroll
      for (int r = 0; r < 4; ++r) {
        const float v = acc[i][j][r] + badd;
        if (OUTF32) ((float*)Cv)[(size_t)(rbase + r) * N + col] = v;
        else        ((u16*)Cv)[(size_t)(rbase + r) * N + col] = f2bf(v);
      }
    }
  }
}

// ---------------------------------------------------------------------------
// XCA attention core. One block (256 thr, 4 waves) per (b,h).
// qkv layout: [B,N,3,H,48] bf16 -> elem(b,n,s,h,d) = (b*1024+n)*2304 + s*768
//                                                    + h*48 + d
// Phase 1: sumsq over n of q,k rows; Phase 2: attn = qhat@khat^T via MFMA
// (K=1024 split across waves, LDS-atomic reduce); Phase 3: row softmax with
// fp32 temperature; Phase 4: out = attn@v via MFMA, writes [B,N,C] bf16.
// ---------------------------------------------------------------------------
__global__ __launch_bounds__(256)
void xca_attn_kernel(const u16* __restrict__ qkv,
                     const float* __restrict__ temperature,
                     u16* __restrict__ aout) {
  const int tid = threadIdx.x;
  const int l = tid & 63, w = tid >> 6;
  const int lane16 = l & 15, lg = l >> 4;
  const int bh = blockIdx.x, b = bh >> 4, h = bh & 15;
  const size_t base = (size_t)b * 1024 * 2304 + (size_t)h * 48;

  __shared__ alignas(16) u16 qt[4][48][32];        // 12 KB (per-wave tiles)
  __shared__ alignas(16) u16 kt[4][48][32];        // 12 KB
  __shared__ alignas(16) u16 vt[4][16][64];        // 8 KB
  __shared__ alignas(16) float attn_raw[48][48];   // 9 KB
  __shared__ alignas(16) u16 attn_bf[48][64];      // 6 KB
  __shared__ float rnq[48], rnk[48];
  __shared__ float sq_q[16][48], sq_k[16][48];     // 6 KB

  // ---- phase 1: sum of squares along n for q and k rows ----
  if (tid < 192) {
    const int dq = tid % 12, g = tid / 12;   // d = dq*4, 16 n-groups
    const int d = dq * 4;
    float aq0 = 0, aq1 = 0, aq2 = 0, aq3 = 0;
    float ak0 = 0, ak1 = 0, ak2 = 0, ak3 = 0;
    for (int n = g; n < 1024; n += 16) {
      const size_t o = base + (size_t)n * 2304 + d;
      ushort4 qv = *(const ushort4*)&qkv[o];
      ushort4 kv = *(const ushort4*)&qkv[o + 768];
      float f;
      f = bf2f(qv.x); aq0 += f * f;  f = bf2f(qv.y); aq1 += f * f;
      f = bf2f(qv.z); aq2 += f * f;  f = bf2f(qv.w); aq3 += f * f;
      f = bf2f(kv.x); ak0 += f * f;  f = bf2f(kv.y); ak1 += f * f;
      f = bf2f(kv.z); ak2 += f * f;  f = bf2f(kv.w); ak3 += f * f;
    }
    sq_q[g][d + 0] = aq0; sq_q[g][d + 1] = aq1;
    sq_q[g][d + 2] = aq2; sq_q[g][d + 3] = aq3;
    sq_k[g][d + 0] = ak0; sq_k[g][d + 1] = ak1;
    sq_k[g][d + 2] = ak2; sq_k[g][d + 3] = ak3;
  }
  for (int i = tid; i < 48 * 48; i += 256) ((float*)attn_raw)[i] = 0.f;
  __syncthreads();
  if (tid < 48) {
    float s = 0.f, s2 = 0.f;
#pragma unroll
    for (int g = 0; g < 16; ++g) { s += sq_q[g][tid]; s2 += sq_k[g][tid]; }
    rnq[tid] = 1.f / fmaxf(sqrtf(s), 1e-12f);
    rnk[tid] = 1.f / fmaxf(sqrtf(s2), 1e-12f);
  }
  __syncthreads();

  // ---- phase 2: attn_raw = qhat @ khat^T (K=1024 split across waves) ----
  const f32x4 zero = {0.f, 0.f, 0.f, 0.f};
  f32x4 pacc[3][3];
#pragma unroll
  for (int i = 0; i < 3; ++i)
#pragma unroll
    for (int j = 0; j < 3; ++j) pacc[i][j] = zero;

  for (int s = 0; s < 8; ++s) {
    const int n0 = (s * 4 + w) * 32;
    for (int idx = l; idx < 384; idx += 64) {     // 32 nl * 12 dq
      const int nl = idx / 12, dq = idx - nl * 12, d = dq * 4;
      const size_t o = base + (size_t)(n0 + nl) * 2304 + d;
      ushort4 qv = *(const ushort4*)&qkv[o];
      ushort4 kv = *(const ushort4*)&qkv[o + 768];
      qt[w][d + 0][nl] = f2bf(bf2f(qv.x) * rnq[d + 0]);
      qt[w][d + 1][nl] = f2bf(bf2f(qv.y) * rnq[d + 1]);
      qt[w][d + 2][nl] = f2bf(bf2f(qv.z) * rnq[d + 2]);
      qt[w][d + 3][nl] = f2bf(bf2f(qv.w) * rnq[d + 3]);
      kt[w][d + 0][nl] = f2bf(bf2f(kv.x) * rnk[d + 0]);
      kt[w][d + 1][nl] = f2bf(bf2f(kv.y) * rnk[d + 1]);
      kt[w][d + 2][nl] = f2bf(bf2f(kv.z) * rnk[d + 2]);
      kt[w][d + 3][nl] = f2bf(bf2f(kv.w) * rnk[d + 3]);
    }
    __syncthreads();
    bf16x8 qf[3], kf[3];
#pragma unroll
    for (int i = 0; i < 3; ++i)
      qf[i] = *(const bf16x8*)&qt[w][i * 16 + lane16][lg * 8];
#pragma unroll
    for (int j = 0; j < 3; ++j)
      kf[j] = *(const bf16x8*)&kt[w][j * 16 + lane16][lg * 8];
#pragma unroll
    for (int i = 0; i < 3; ++i)
#pragma unroll
      for (int j = 0; j < 3; ++j)
        pacc[i][j] = __builtin_amdgcn_mfma_f32_16x16x32_bf16(qf[i], kf[j], pacc[i][j], 0, 0, 0);
    __syncthreads();
  }
#pragma unroll
  for (int i = 0; i < 3; ++i)
#pragma unroll
    for (int j = 0; j < 3; ++j)
#pragma unroll
      for (int r = 0; r < 4; ++r)
        atomicAdd(&attn_raw[i * 16 + lg * 4 + r][j * 16 + lane16], pacc[i][j][r]);
  __syncthreads();

  // ---- phase 3: row softmax with temperature ----
  const float temp = temperature[h];
  if (tid < 48) {
    float m = -1e30f;
    for (int e = 0; e < 48; ++e) m = fmaxf(m, attn_raw[tid][e] * temp);
    float ssum = 0.f;
    for (int e = 0; e < 48; ++e) {
      float p = __expf(attn_raw[tid][e] * temp - m);
      attn_raw[tid][e] = p; ssum += p;
    }
    const float inv = 1.f / ssum;
    for (int e = 0; e < 48; ++e) attn_bf[tid][e] = f2bf(attn_raw[tid][e] * inv);
    for (int e = 48; e < 64; ++e) attn_bf[tid][e] = 0;
  }
  // zero the K-padding columns of vt (cols 48..63)
  for (int idx = tid; idx < 4 * 16 * 16; idx += 256) {
    const int ww = idx >> 8, rr = (idx >> 4) & 15, ee = idx & 15;
    vt[ww][rr][48 + ee] = 0;
  }
  __syncthreads();

  // ---- phase 4: out = attn @ v ----
  bf16x8 af2[3][2];
#pragma unroll
  for (int i = 0; i < 3; ++i)
#pragma unroll
    for (int ks = 0; ks < 2; ++ks)
      af2[i][ks] = *(const bf16x8*)&attn_bf[i * 16 + lane16][ks * 32 + lg * 8];

  for (int nf = 0; nf < 16; ++nf) {
    const int n0 = w * 256 + nf * 16;
    for (int idx = l; idx < 192; idx += 64) {    // 16 nl * 12 eq (ushort4)
      const int nl = idx / 12, e = (idx - nl * 12) * 4;
      *(ushort4*)&vt[w][nl][e] =
          *(const ushort4*)&qkv[base + 1536 + (size_t)(n0 + nl) * 2304 + e];
    }
    __syncthreads();
    bf16x8 vf0 = *(const bf16x8*)&vt[w][lane16][lg * 8];
    bf16x8 vf1 = *(const bf16x8*)&vt[w][lane16][32 + lg * 8];
#pragma unroll
    for (int i = 0; i < 3; ++i) {
      f32x4 acc = zero;
      acc = __builtin_amdgcn_mfma_f32_16x16x32_bf16(af2[i][0], vf0, acc, 0, 0, 0);
      acc = __builtin_amdgcn_mfma_f32_16x16x32_bf16(af2[i][1], vf1, acc, 0, 0, 0);
      const int n = n0 + lane16;
      const size_t oo = (size_t)(b * 1024 + n) * 768 + h * 48 + i * 16 + lg * 4;
      ushort4 pack;
      pack.x = f2bf(acc[0]); pack.y = f2bf(acc[1]);
      pack.z = f2bf(acc[2]); pack.w = f2bf(acc[3]);
      *(ushort4*)&aout[oo] = pack;
    }
    __syncthreads();
  }
}

// ---------------------------------------------------------------------------
extern "C" void kernel_launch(void* const* d_in, const int* in_sizes, int n_in,
                              void* d_out, int out_size, void* d_ws, size_t ws_size,
                              hipStream_t stream) {
  // ALL inputs and the output are FP32 (reference dtypes).
  const float* x      = (const float*)d_in[0];  // [32768][768]
  const float* w_qkv  = (const float*)d_in[1];  // [2304][768]
  const float* w_proj = (const float*)d_in[2];  // [768][768]
  const float* b_proj = (const float*)d_in[3];  // [768]
  const float* temp   = (const float*)d_in[4];  // [16]
  float* out = (float*)d_out;                   // [32768][768]

  // bf16 scratch layout.
  // x_bf lives in d_out (dead until GEMM2 overwrites the whole buffer).
  u16* x_bf = (u16*)d_out;                                  // 50.3 MB
  char* ws = (char*)d_ws;
  u16* qkvb      = (u16*)ws;                                // 151.0 MB
  u16* aoutb     = (u16*)(ws + (size_t)150994944);          // 50.3 MB
  u16* w_qkv_bf  = (u16*)(ws + (size_t)201326592);          // 3.54 MB
  u16* w_proj_bf = (u16*)(ws + (size_t)204865536);          // 1.18 MB
  // total ws use: ~206.05 MB

  dim3 blk(256);
  // casts (all sizes divisible by 1024)
  cast_f32_bf16_kernel<<<dim3(32768 * 768 / 1024), blk, 0, stream>>>(
      x, x_bf, 32768 * 768);
  cast_f32_bf16_kernel<<<dim3(2304 * 768 / 1024), blk, 0, stream>>>(
      w_qkv, w_qkv_bf, 2304 * 768);
  cast_f32_bf16_kernel<<<dim3(768 * 768 / 1024), blk, 0, stream>>>(
      w_proj, w_proj_bf, 768 * 768);

  // qkv = x @ w_qkv^T  (bf16 out)
  gemm_bt_kernel<0, 0><<<dim3(256, 18), blk, 0, stream>>>(
      x_bf, w_qkv_bf, qkvb, nullptr, 32768, 2304, 768);
  // attention core -> aoutb [B,N,C] bf16
  xca_attn_kernel<<<dim3(512), blk, 0, stream>>>(qkvb, temp, aoutb);
  // out = aoutb @ w_proj^T + b_proj  (fp32 out)
  gemm_bt_kernel<1, 1><<<dim3(256, 6), blk, 0, stream>>>(
      aoutb, w_proj_bf, out, b_proj, 32768, 768, 768);
}

// Round 4
// 333.116 us; speedup vs baseline: 1.1811x; 1.1811x over previous
//
#include <hip/hip_runtime.h>
#include <hip/hip_bf16.h>

typedef unsigned short u16;
typedef __bf16 bf16x8 __attribute__((ext_vector_type(8)));
typedef u16 u16x8 __attribute__((ext_vector_type(8)));
typedef float f32x4 __attribute__((ext_vector_type(4)));

__device__ __forceinline__ float bf2f(u16 u) {
  union { unsigned u32; float f; } c; c.u32 = ((unsigned)u) << 16; return c.f;
}
__device__ __forceinline__ u16 f2bf(float f) {
  union { float f; unsigned u32; } c; c.f = f;
  unsigned r = c.u32 + 0x7FFFu + ((c.u32 >> 16) & 1u);
  return (u16)(r >> 16);
}

#define GLD16(gp, lp) __builtin_amdgcn_global_load_lds( \
    (const __attribute__((address_space(1))) void*)(gp), \
    (__attribute__((address_space(3))) void*)(lp), 16, 0, 0)

// ---------------------------------------------------------------------------
// fp32 -> bf16 cast, 4 elems/thread.
// ---------------------------------------------------------------------------
__global__ __launch_bounds__(256)
void cast_f32_bf16_kernel(const float* __restrict__ in, u16* __restrict__ out,
                          int n4) {
  const int i = (blockIdx.x * 256 + threadIdx.x) * 4;
  if (i < n4) {
    float4 v = *(const float4*)(in + i);
    ushort4 o;
    o.x = f2bf(v.x); o.y = f2bf(v.y); o.z = f2bf(v.z); o.w = f2bf(v.w);
    *(ushort4*)(out + i) = o;
  }
}

// ---------------------------------------------------------------------------
// GEMM (m97 structure): C[M,N] = A[M,K] @ B[N,K]^T, bf16 in, fp32 accum,
// bf16 or fp32(+bias) out. 128x128 tile, BK=32, 4 waves, global_load_lds
// width-16 staging, linear [128][32] LDS. 1-D grid with bijective XCD
// swizzle; bn-fastest ordering so co-resident blocks on one XCD share
// A-tiles (B fits in every per-XCD L2).
// ---------------------------------------------------------------------------
template<int BIAS, int OUTF32>
__global__ __launch_bounds__(256)
void gemm_bt_kernel(const u16* __restrict__ A, const u16* __restrict__ B,
                    void* __restrict__ Cv, const float* __restrict__ bias,
                    int M, int N, int K, int nbn) {
  __shared__ alignas(16) u16 As[128][32];   // 8 KB
  __shared__ alignas(16) u16 Bs[128][32];   // 8 KB
  const int tid = threadIdx.x;
  const int l = tid & 63, w = tid >> 6;
  const int lane16 = l & 15, lg = l >> 4;
  const int wr = w >> 1, wc = w & 1;
  // bijective XCD swizzle (gridDim.x % 8 == 0 guaranteed by launch)
  const int cpx = gridDim.x >> 3;
  const int swz = (blockIdx.x & 7) * cpx + (blockIdx.x >> 3);
  const int bm = swz / nbn, bn = swz - bm * nbn;

  const f32x4 zero = {0.f, 0.f, 0.f, 0.f};
  f32x4 acc[4][4];
#pragma unroll
  for (int i = 0; i < 4; ++i)
#pragma unroll
    for (int j = 0; j < 4; ++j) acc[i][j] = zero;

  // chunk c in [0,512) covers elems [c*8,c*8+8) of [128][32]; LDS byte c*16.
  // Round r, wave w, lane l -> c = r*256 + w*64 + l; dest = wave base + l*16.
  const int r0 = tid >> 2, e0 = (tid & 3) * 8;
  const u16* Ap0 = A + (size_t)(bm * 128 + r0) * K + e0;
  const u16* Ap1 = A + (size_t)(bm * 128 + r0 + 64) * K + e0;
  const u16* Bp0 = B + (size_t)(bn * 128 + r0) * K + e0;
  const u16* Bp1 = B + (size_t)(bn * 128 + r0 + 64) * K + e0;

  for (int k0 = 0; k0 < K; k0 += 32) {
    GLD16(Ap0 + k0, (char*)&As[0][0] + w * 1024);
    GLD16(Ap1 + k0, (char*)&As[0][0] + 4096 + w * 1024);
    GLD16(Bp0 + k0, (char*)&Bs[0][0] + w * 1024);
    GLD16(Bp1 + k0, (char*)&Bs[0][0] + 4096 + w * 1024);
    __syncthreads();   // compiler emits vmcnt(0) drain before s_barrier

    bf16x8 af[4], bfr[4];
#pragma unroll
    for (int i = 0; i < 4; ++i)
      af[i] = *(const bf16x8*)&As[wr * 64 + i * 16 + lane16][lg * 8];
#pragma unroll
    for (int j = 0; j < 4; ++j)
      bfr[j] = *(const bf16x8*)&Bs[wc * 64 + j * 16 + lane16][lg * 8];
#pragma unroll
    for (int i = 0; i < 4; ++i)
#pragma unroll
      for (int j = 0; j < 4; ++j)
        acc[i][j] = __builtin_amdgcn_mfma_f32_16x16x32_bf16(af[i], bfr[j], acc[i][j], 0, 0, 0);
    __syncthreads();   // reads done before next iter's staging
  }

  // epilogue: D layout col = lane&15, row = (lane>>4)*4 + reg
  const int row0 = bm * 128 + wr * 64, col0 = bn * 128 + wc * 64;
#pragma unroll
  for (int i = 0; i < 4; ++i) {
#pragma unroll
    for (int j = 0; j < 4; ++j) {
      const int col = col0 + j * 16 + lane16;
      const float badd = BIAS ? bias[col] : 0.f;
      const int rbase = row0 + i * 16 + lg * 4;
#pragma unroll
      for (int r = 0; r < 4; ++r) {
        const float v = acc[i][j][r] + badd;
        if (OUTF32) ((float*)Cv)[(size_t)(rbase + r) * N + col] = v;
        else        ((u16*)Cv)[(size_t)(rbase + r) * N + col] = f2bf(v);
      }
    }
  }
}

// ---------------------------------------------------------------------------
// XCA attention core v2. One block (256 thr, 4 waves) per (b,h).
// qkv: [B,N,3,H,48] bf16.
// Key restructure vs v1:
//  - normalize AFTER QK^T: attn = diag(rnq) (q k^T) diag(rnk)  -> staging is
//    a pure bf16 transpose copy (no f2bf/mul).
//  - sumsq via MFMA: diag(q q^T), diag(k k^T) accumulated alongside QK^T;
//    phase-1 re-read of q,k eliminated.
//  - per-wave LDS tiles, ordered by lgkmcnt (no barriers in hot loop).
//  - phase 4 loads V fragments straight from global (no LDS, no barriers).
// ---------------------------------------------------------------------------
__global__ __launch_bounds__(256)
void xca_attn_kernel(const u16* __restrict__ qkv,
                     const float* __restrict__ temperature,
                     u16* __restrict__ aout) {
  const int tid = threadIdx.x;
  const int l = tid & 63, w = tid >> 6;
  const int lane16 = l & 15, lg = l >> 4;
  const int bh = blockIdx.x, b = bh >> 4, h = bh & 15;
  const size_t base = (size_t)b * 1024 * 2304 + (size_t)h * 48;

  __shared__ alignas(16) u16 qt[4][48][32];        // 12 KB, per-wave
  __shared__ alignas(16) u16 kt[4][48][32];        // 12 KB, per-wave
  __shared__ alignas(16) float attn_raw[48][48];   // 9 KB
  __shared__ alignas(16) u16 attn_bf[48][64];      // 6 KB
  __shared__ float sqs[2][48];                     // sumsq q,k
  __shared__ float rn[2][48];                      // 1/max(norm,eps)

  // zero reduction buffers
  for (int i = tid; i < 48 * 48; i += 256) ((float*)attn_raw)[i] = 0.f;
  if (tid < 96) ((float*)sqs)[tid] = 0.f;
  __syncthreads();

  const f32x4 zero = {0.f, 0.f, 0.f, 0.f};
  f32x4 pqk[3][3], pqq[3], pkk[3];
#pragma unroll
  for (int i = 0; i < 3; ++i) {
    pqq[i] = zero; pkk[i] = zero;
#pragma unroll
    for (int j = 0; j < 3; ++j) pqk[i][j] = zero;
  }

  // ---- phase 2: QK^T + QQ^T/KK^T diag blocks, K=1024 over 8 s-iters ----
  for (int s = 0; s < 8; ++s) {
    const int n0 = (s * 4 + w) * 32;
    // stage raw q,k [48][32] via in-register 4x4 transpose.
    // 192 tasks: mat(2) x dblk(12) x nblk(8); 3 per lane.
#pragma unroll
    for (int t0 = 0; t0 < 3; ++t0) {
      const int t = t0 * 64 + l;
      const int mat = t >= 96;
      const int tt = t - mat * 96;
      const int d0 = (tt % 12) * 4, nl0 = (tt / 12) * 4;
      const u16* src = qkv + base + (size_t)(n0 + nl0) * 2304 + mat * 768 + d0;
      ushort4 r0 = *(const ushort4*)(src);
      ushort4 r1 = *(const ushort4*)(src + 2304);
      ushort4 r2 = *(const ushort4*)(src + 4608);
      ushort4 r3 = *(const ushort4*)(src + 6912);
      u16 (*dst)[32] = mat ? kt[w] : qt[w];
      ushort4 c;
      c.x = r0.x; c.y = r1.x; c.z = r2.x; c.w = r3.x; *(ushort4*)&dst[d0 + 0][nl0] = c;
      c.x = r0.y; c.y = r1.y; c.z = r2.y; c.w = r3.y; *(ushort4*)&dst[d0 + 1][nl0] = c;
      c.x = r0.z; c.y = r1.z; c.z = r2.z; c.w = r3.z; *(ushort4*)&dst[d0 + 2][nl0] = c;
      c.x = r0.w; c.y = r1.w; c.z = r2.w; c.w = r3.w; *(ushort4*)&dst[d0 + 3][nl0] = c;
    }
    // per-wave tile: order writes->reads within the wave (DS pipe in-order,
    // plus explicit fence so compiler can't sink reads above)
    asm volatile("s_waitcnt lgkmcnt(0)" ::: "memory");
    __builtin_amdgcn_sched_barrier(0);

    bf16x8 qf[3], kf[3];
#pragma unroll
    for (int i = 0; i < 3; ++i)
      qf[i] = *(const bf16x8*)&qt[w][i * 16 + lane16][lg * 8];
#pragma unroll
    for (int j = 0; j < 3; ++j)
      kf[j] = *(const bf16x8*)&kt[w][j * 16 + lane16][lg * 8];
#pragma unroll
    for (int i = 0; i < 3; ++i)
#pragma unroll
      for (int j = 0; j < 3; ++j)
        pqk[i][j] = __builtin_amdgcn_mfma_f32_16x16x32_bf16(qf[i], kf[j], pqk[i][j], 0, 0, 0);
#pragma unroll
    for (int i = 0; i < 3; ++i) {
      pqq[i] = __builtin_amdgcn_mfma_f32_16x16x32_bf16(qf[i], qf[i], pqq[i], 0, 0, 0);
      pkk[i] = __builtin_amdgcn_mfma_f32_16x16x32_bf16(kf[i], kf[i], pkk[i], 0, 0, 0);
    }
  }

  // reduce partial sums into LDS
#pragma unroll
  for (int i = 0; i < 3; ++i)
#pragma unroll
    for (int j = 0; j < 3; ++j)
#pragma unroll
      for (int r = 0; r < 4; ++r)
        atomicAdd(&attn_raw[i * 16 + lg * 4 + r][j * 16 + lane16], pqk[i][j][r]);
  // diag of qq^T/kk^T: element (d,d), d=i*16+lane16, held where lg==lane16>>2
  if (lg == (lane16 >> 2)) {
    const int r = lane16 & 3;
#pragma unroll
    for (int i = 0; i < 3; ++i) {
      atomicAdd(&sqs[0][i * 16 + lane16], pqq[i][r]);
      atomicAdd(&sqs[1][i * 16 + lane16], pkk[i][r]);
    }
  }
  __syncthreads();

  if (tid < 96) {
    const int m = tid / 48, d = tid % 48;
    rn[m][d] = 1.f / fmaxf(sqrtf(sqs[m][d]), 1e-12f);
  }
  __syncthreads();

  // ---- phase 3: row softmax, post-scaled by rnq[d]*rnk[e]*temp ----
  const float temp = temperature[h];
  if (tid < 48) {
    const float sr = rn[0][tid] * temp;
    float mx = -1e30f;
    for (int e = 0; e < 48; ++e)
      mx = fmaxf(mx, attn_raw[tid][e] * rn[1][e] * sr);
    float ssum = 0.f;
    for (int e = 0; e < 48; ++e) {
      const float p = __expf(attn_raw[tid][e] * rn[1][e] * sr - mx);
      attn_raw[tid][e] = p; ssum += p;
    }
    const float inv = 1.f / ssum;
    for (int e = 0; e < 48; ++e) attn_bf[tid][e] = f2bf(attn_raw[tid][e] * inv);
    for (int e = 48; e < 64; ++e) attn_bf[tid][e] = 0;
  }
  __syncthreads();

  // ---- phase 4: out = attn @ v, V fragments direct from global ----
  bf16x8 af2[3][2];
#pragma unroll
  for (int i = 0; i < 3; ++i)
#pragma unroll
    for (int ks = 0; ks < 2; ++ks)
      af2[i][ks] = *(const bf16x8*)&attn_bf[i * 16 + lane16][ks * 32 + lg * 8];

  const bf16x8 zf = {0, 0, 0, 0, 0, 0, 0, 0};
  for (int nf = 0; nf < 16; ++nf) {
    const int n0 = w * 256 + nf * 16;
    // B-frag[n=lane16][k=lg*8+j] = v[e=k][n0+lane16]; e in [0,48), pad 0
    const u16* vsrc = qkv + base + 1536 + (size_t)(n0 + lane16) * 2304 + lg * 8;
    bf16x8 vf0 = *(const bf16x8*)vsrc;                        // e 0..31
    bf16x8 vf1 = (lg < 2) ? *(const bf16x8*)(vsrc + 32) : zf; // e 32..47
#pragma unroll
    for (int i = 0; i < 3; ++i) {
      f32x4 acc = zero;
      acc = __builtin_amdgcn_mfma_f32_16x16x32_bf16(af2[i][0], vf0, acc, 0, 0, 0);
      acc = __builtin_amdgcn_mfma_f32_16x16x32_bf16(af2[i][1], vf1, acc, 0, 0, 0);
      const size_t oo = (size_t)(b * 1024 + n0 + lane16) * 768 + h * 48 + i * 16 + lg * 4;
      ushort4 pack;
      pack.x = f2bf(acc[0]); pack.y = f2bf(acc[1]);
      pack.z = f2bf(acc[2]); pack.w = f2bf(acc[3]);
      *(ushort4*)&aout[oo] = pack;
    }
  }
}

// ---------------------------------------------------------------------------
extern "C" void kernel_launch(void* const* d_in, const int* in_sizes, int n_in,
                              void* d_out, int out_size, void* d_ws, size_t ws_size,
                              hipStream_t stream) {
  const float* x      = (const float*)d_in[0];  // [32768][768]
  const float* w_qkv  = (const float*)d_in[1];  // [2304][768]
  const float* w_proj = (const float*)d_in[2];  // [768][768]
  const float* b_proj = (const float*)d_in[3];  // [768]
  const float* temp   = (const float*)d_in[4];  // [16]
  float* out = (float*)d_out;                   // [32768][768]

  // x_bf lives in d_out (dead until GEMM2 overwrites it).
  u16* x_bf = (u16*)d_out;                                  // 50.3 MB
  char* ws = (char*)d_ws;
  u16* qkvb      = (u16*)ws;                                // 151.0 MB
  u16* aoutb     = (u16*)(ws + (size_t)150994944);          // 50.3 MB
  u16* w_qkv_bf  = (u16*)(ws + (size_t)201326592);          // 3.54 MB
  u16* w_proj_bf = (u16*)(ws + (size_t)204865536);          // 1.18 MB

  dim3 blk(256);
  cast_f32_bf16_kernel<<<dim3(32768 * 768 / 1024), blk, 0, stream>>>(
      x, x_bf, 32768 * 768);
  cast_f32_bf16_kernel<<<dim3(2304 * 768 / 1024), blk, 0, stream>>>(
      w_qkv, w_qkv_bf, 2304 * 768);
  cast_f32_bf16_kernel<<<dim3(768 * 768 / 1024), blk, 0, stream>>>(
      w_proj, w_proj_bf, 768 * 768);

  // qkv = x @ w_qkv^T : grid 256x18 -> 4608 blocks (divisible by 8)
  gemm_bt_kernel<0, 0><<<dim3(4608), blk, 0, stream>>>(
      x_bf, w_qkv_bf, qkvb, nullptr, 32768, 2304, 768, 18);
  // attention core -> aoutb [B,N,C] bf16
  xca_attn_kernel<<<dim3(512), blk, 0, stream>>>(qkvb, temp, aoutb);
  // out = aoutb @ w_proj^T + b_proj : 256x6 -> 1536 blocks
  gemm_bt_kernel<1, 1><<<dim3(1536), blk, 0, stream>>>(
      aoutb, w_proj_bf, out, b_proj, 32768, 768, 768, 6);
}